// Round 20
// baseline (106.829 us; speedup 1.0000x reference)
//
#include <hip/hip_runtime.h>
#include <hip/hip_fp16.h>

#define BLK 256
#define PBLK 1024             // threads per partition block
#define NPB 512               // partition blocks == chunks (2 blocks/CU -> full wave fill)
#define CSHIFT 10             // 1024 dst nodes per coarse bucket
#define CNODES 1024
#define CMASK 1023
#define NBCMAX 128            // max coarse buckets (n <= 131072)
#define CAP 40960             // coarse slab slots per bucket (mean ~32.6K + pad ~4K)
#define SSHIFT 6              // slice bits 6..9 -> 16 slices of 64 nodes
#define NSL 16
#define SROWS 64
#define SRMASK 63
#define NCHK 8                // positional chunks per bucket for refine
#define FCAP2 384             // slots per (bucket,slice,chunk); <=96 int4 slots (single-shot)
#define FXS 1048576.0f        // 2^20 fixed-point scale for LDS accumulation
#define FXI (1.0f / 1048576.0f)
#define PBIAS (1 << 23)       // per-addend bias so packed 32+32 halves stay non-negative

typedef int v4i __attribute__((ext_vector_type(4)));
typedef unsigned long long u64;

static inline int cdiv(int a, int b) { return (a + b - 1) / b; }

// ---------------- fused partition: local hist -> atomic run reservation -> scatter ----------------
__global__ void __launch_bounds__(PBLK)
k_part(const int* __restrict__ src, const int* __restrict__ dst,
       int* __restrict__ gcur, int* __restrict__ slab, int e, int nb) {
    __shared__ int hist[4][NBCMAX];
    __shared__ int curs[NBCMAX];
    __shared__ int rend[NBCMAX];
    int tid = threadIdx.x;
    int rep = (tid >> 6) & 3;
    for (int t = tid; t < 4 * NBCMAX; t += PBLK) ((int*)hist)[t] = 0;
    __syncthreads();
    int per = ((e + (int)gridDim.x - 1) / (int)gridDim.x + 3) & ~3;
    int beg = blockIdx.x * per;
    int end = min(e, beg + per);
    // pass 1: local histogram (cached loads -> chunk becomes L2-resident)
    if (beg < end) {
        int m4 = beg + ((end - beg) & ~3);
        for (int i = beg + tid * 4; i < m4; i += PBLK * 4) {
            v4i d4 = *reinterpret_cast<const v4i*>(dst + i);
            atomicAdd(&hist[rep][d4[0] >> CSHIFT], 1);
            atomicAdd(&hist[rep][d4[1] >> CSHIFT], 1);
            atomicAdd(&hist[rep][d4[2] >> CSHIFT], 1);
            atomicAdd(&hist[rep][d4[3] >> CSHIFT], 1);
        }
        int it = m4 + tid;
        if (it < end) atomicAdd(&hist[rep][dst[it] >> CSHIFT], 1);
    }
    __syncthreads();
    // reserve 16-aligned runs via one global atomic per (block,bucket)
    for (int b = tid; b < nb; b += PBLK) {
        int cnt = hist[0][b] + hist[1][b] + hist[2][b] + hist[3][b];
        int r16 = (cnt + 15) & ~15;
        int base = 0;
        if (r16) base = atomicAdd(&gcur[b], r16);
        int a0 = b * CAP + min(base, CAP);
        int a1 = b * CAP + min(base + r16, CAP);
        curs[b] = a0;
        rend[b] = a1;
    }
    __syncthreads();
    // pass 2: scatter (reads hit L2)
    if (beg < end) {
        int m4 = beg + ((end - beg) & ~3);
        for (int i = beg + tid * 4; i < m4; i += PBLK * 4) {
            v4i s4 = *reinterpret_cast<const v4i*>(src + i);
            v4i d4 = *reinterpret_cast<const v4i*>(dst + i);
#pragma unroll
            for (int k = 0; k < 4; ++k) {
                int d = d4[k];
                int b = d >> CSHIFT;
                int pos = atomicAdd(&curs[b], 1);
                if (pos < rend[b]) slab[pos] = (s4[k] << CSHIFT) | (d & CMASK);
            }
        }
        int it = m4 + tid;
        if (it < end) {
            int d = dst[it];
            int b = d >> CSHIFT;
            int pos = atomicAdd(&curs[b], 1);
            if (pos < rend[b]) slab[pos] = (src[it] << CSHIFT) | (d & CMASK);
        }
    }
    __syncthreads();
    // pad run tails to the 16-aligned reservation end with -1
    for (int b = tid; b < nb; b += PBLK) {
        for (int x = curs[b]; x < rend[b]; ++x) slab[x] = -1;
    }
}

// ---------------- pass D: chunked refine -> 16 fine segments per (bucket,chunk) + degree ----------------
__global__ void __launch_bounds__(PBLK)
k_refine(const int* __restrict__ tot, const int* __restrict__ cslab,
         int* __restrict__ fslab, int* __restrict__ ftot,
         int* __restrict__ deg, int n) {
    __shared__ int cur[NSL];
    __shared__ int cnt[CNODES];
    int tid = threadIdx.x;
    int b = blockIdx.x >> 3;
    int p = blockIdx.x & 7;
    if (tid < NSL) cur[tid] = 0;
    for (int t = tid; t < CNODES; t += PBLK) cnt[t] = 0;
    __syncthreads();
    int nlines = min(tot[b], CAP) >> 4;       // tot is a multiple of 16
    int q0 = ((p * nlines) >> 3) << 2;        // chunk start, int4 units (16-aligned slots)
    int q1 = (((p + 1) * nlines) >> 3) << 2;  // chunk end
    const v4i* sl4 = reinterpret_cast<const v4i*>(cslab + (size_t)b * CAP);
    for (int i = q0 + tid; i < q1; i += PBLK) {
        v4i e4 = sl4[i];
#pragma unroll
        for (int k = 0; k < 4; ++k) {
            int e = e4[k];
            if (e >= 0) {
                int s = (e >> SSHIFT) & (NSL - 1);
                int fe = ((e >> CSHIFT) << SSHIFT) | (e & SRMASK);
                atomicAdd(&cnt[e & CMASK], 1);
                int pos = atomicAdd(&cur[s], 1);
                if (pos < FCAP2) fslab[(size_t)((b * NSL + s) * NCHK + p) * FCAP2 + pos] = fe;
            }
        }
    }
    __syncthreads();
    if (tid < NSL) {
        int cc = min(cur[tid], FCAP2);
        int r = min((cc + 15) & ~15, FCAP2);
        int* seg = fslab + (size_t)((b * NSL + tid) * NCHK + p) * FCAP2;
        for (int x = cc; x < r; ++x) seg[x] = -1;
        ftot[(b * NSL + tid) * NCHK + p] = r;
    }
    for (int t = tid; t < CNODES; t += PBLK) {
        int v = cnt[t];
        int nd = b * CNODES + t;
        if (v && nd < n) atomicAdd(&deg[nd], v);
    }
}

// ---------------- fused: feature encode -> @W0 -> *dinv -> Hs[n,16] (f16) ----------------
__global__ void k_featmm(const int* __restrict__ feat,
                         const float* __restrict__ emb_user,
                         const float* __restrict__ emb_known,
                         const float* __restrict__ w_user,
                         const float* __restrict__ b_user,
                         const float* __restrict__ emb_cat,
                         const float* __restrict__ w_cat,
                         const float* __restrict__ b_cat,
                         const float* __restrict__ w0,
                         const int* __restrict__ deg,
                         __half* __restrict__ Hs,
                         int n, int user_max, int cat_max) {
    __shared__ float w0s[8 * 16];
    for (int t = threadIdx.x; t < 8 * 16; t += blockDim.x) w0s[t] = w0[t];
    __syncthreads();
    int i = blockIdx.x * blockDim.x + threadIdx.x;
    if (i >= n) return;
    int col0 = feat[i * 3 + 0];
    int col1 = feat[i * 3 + 1];
    int typ  = feat[i * 3 + 2];
    float x[8];
    if (typ == 0) {
        int u = min(max(col0, 0), user_max);
        int k = min(max(col1, 0), 1);
        const float4* eu = reinterpret_cast<const float4*>(emb_user + (size_t)u * 8);
        const float4* ek = reinterpret_cast<const float4*>(emb_known + (size_t)k * 8);
        float4 a0 = eu[0], a1 = eu[1], k0 = ek[0], k1 = ek[1];
        float in[8];
        in[0] = fmaxf(a0.x + k0.x, 0.f); in[1] = fmaxf(a0.y + k0.y, 0.f);
        in[2] = fmaxf(a0.z + k0.z, 0.f); in[3] = fmaxf(a0.w + k0.w, 0.f);
        in[4] = fmaxf(a1.x + k1.x, 0.f); in[5] = fmaxf(a1.y + k1.y, 0.f);
        in[6] = fmaxf(a1.z + k1.z, 0.f); in[7] = fmaxf(a1.w + k1.w, 0.f);
#pragma unroll
        for (int c = 0; c < 8; ++c) {
            float s = b_user[c];
#pragma unroll
            for (int d = 0; d < 8; ++d) s += in[d] * w_user[d * 8 + c];
            x[c] = s;
        }
    } else {
        int ci = min(max(col0, 0), cat_max);
        float4 c0 = reinterpret_cast<const float4*>(emb_cat + (size_t)ci * 4)[0];
        float in[4];
        in[0] = fmaxf(c0.x, 0.f); in[1] = fmaxf(c0.y, 0.f);
        in[2] = fmaxf(c0.z, 0.f); in[3] = fmaxf(c0.w, 0.f);
#pragma unroll
        for (int c = 0; c < 8; ++c) {
            float s = b_cat[c];
#pragma unroll
            for (int d = 0; d < 4; ++d) s += in[d] * w_cat[d * 8 + c];
            x[c] = s;
        }
    }
    float dv = rsqrtf((float)deg[i] + 1.0f);
    float o[16];
#pragma unroll
    for (int c = 0; c < 16; ++c) {
        float s = 0.f;
#pragma unroll
        for (int d = 0; d < 8; ++d) s += x[d] * w0s[d * 16 + c];
        o[c] = s * dv;
    }
    union { __half2 h[8]; uint4 u[2]; } pk;
#pragma unroll
    for (int k = 0; k < 8; ++k) pk.h[k] = __floats2half2_rn(o[2 * k], o[2 * k + 1]);
    uint4* dp = reinterpret_cast<uint4*>(Hs + (size_t)i * 16);
    dp[0] = pk.u[0];
    dp[1] = pk.u[1];
}

// ---------------- pipelined gather over 4 pair-phases, packed u64 LDS atomics ----------------
// FCAP2 <= 512 guarantees each segment is <=128 int4 slots -> single-shot per pair.
// Next pair's entry vectors are prefetched before the current pair's gathers/atomics.
__device__ __forceinline__ void gather_fb(const int* __restrict__ ftot,
                                          const int* __restrict__ fslab,
                                          int fb, const uint4* __restrict__ Hs4,
                                          u64 (*acc64)[9], int tid) {
    const int LIM = (FCAP2 >> 2) - 1;
    int g = tid >> 1, q = tid & 1;    // 128 lane-pairs; q owns channels 8q..8q+7
    int gi = min(g, LIM);
    // prologue: pair 0 (segments 0,1)
    v4i e0 = reinterpret_cast<const v4i*>(fslab + (size_t)(fb * NCHK + 0) * FCAP2)[gi];
    v4i e1 = reinterpret_cast<const v4i*>(fslab + (size_t)(fb * NCHK + 1) * FCAP2)[gi];
    int ns0 = ftot[fb * NCHK + 0] >> 2;
    int ns1 = ftot[fb * NCHK + 1] >> 2;
#pragma unroll
    for (int p = 0; p < NCHK; p += 2) {
        v4i f0 = e0, f1 = e1;
        int ms0 = 0, ms1 = 0;
        if (p + 2 < NCHK) {   // prefetch next pair
            f0 = reinterpret_cast<const v4i*>(fslab + (size_t)(fb * NCHK + p + 2) * FCAP2)[gi];
            f1 = reinterpret_cast<const v4i*>(fslab + (size_t)(fb * NCHK + p + 3) * FCAP2)[gi];
            ms0 = ftot[fb * NCHK + p + 2] >> 2;
            ms1 = ftot[fb * NCHK + p + 3] >> 2;
        }
        bool b0 = g < ns0, b1 = g < ns1;
        int us[8];
        us[0] = b0 ? e0[0] : -1; us[1] = b0 ? e0[1] : -1;
        us[2] = b0 ? e0[2] : -1; us[3] = b0 ? e0[3] : -1;
        us[4] = b1 ? e1[0] : -1; us[5] = b1 ? e1[1] : -1;
        us[6] = b1 ? e1[2] : -1; us[7] = b1 ? e1[3] : -1;
        uint4 v[8];
#pragma unroll
        for (int k = 0; k < 8; ++k)
            if (us[k] >= 0) v[k] = Hs4[(size_t)(us[k] >> SSHIFT) * 2 + q];
#pragma unroll
        for (int k = 0; k < 8; ++k) {
            if (us[k] >= 0) {
                int dl = us[k] & SRMASK;
                union { uint4 u4; __half2 h[4]; } c;
                c.u4 = v[k];
#pragma unroll
                for (int j = 0; j < 4; ++j) {
                    float2 f = __half22float2(c.h[j]);
                    unsigned a0 = (unsigned)(__float2int_rn(f.x * FXS) + PBIAS);
                    unsigned a1 = (unsigned)(__float2int_rn(f.y * FXS) + PBIAS);
                    u64 pk = ((u64)a1 << 32) | (u64)a0;
                    atomicAdd(&acc64[dl][q * 4 + j], pk);
                }
            }
        }
        e0 = f0; e1 = f1; ns0 = ms0; ns1 = ms1;
    }
}

// unpack channel c for node: acc64[node][c>>1], minus deg*BIAS
__device__ __forceinline__ float unpack_acc(const u64 (*acc64)[9], int node, int c, int dg) {
    u64 w = acc64[node][c >> 1];
    unsigned raw = (c & 1) ? (unsigned)(w >> 32) : (unsigned)(w & 0xffffffffULL);
    long long t = (long long)raw - (long long)dg * PBIAS;
    return (float)t * FXI;
}

// ---------------- conv1: gather + parallel finalize + fused @W2*dinv -> Hs2 (f16) ----------------
__global__ void __launch_bounds__(BLK, 8)
k_bconv1(const int* __restrict__ ftot, const int* __restrict__ fslab,
         const __half* __restrict__ Hs, const int* __restrict__ deg,
         const float* __restrict__ b0, const float* __restrict__ w2,
         __half* __restrict__ Hs2, int n) {
    __shared__ u64 acc64[SROWS][9];
    __shared__ float w2s[16 * 16];
    __shared__ float b0s[16];
    int tid = threadIdx.x;
    for (int t = tid; t < SROWS * 9; t += BLK) ((u64*)acc64)[t] = 0ull;
    w2s[tid] = w2[tid];          // BLK == 256 == 16*16
    if (tid < 16) b0s[tid] = b0[tid];
    __syncthreads();
    int fb = blockIdx.x;
    gather_fb(ftot, fslab, fb, reinterpret_cast<const uint4*>(Hs), acc64, tid);
    __syncthreads();
    // parallel finalize: thread (node = tid&63, qq = tid>>6) computes 4 output channels
    int node = tid & 63;
    int qq = tid >> 6;
    int nd = (fb >> 4) * CNODES + (fb & (NSL - 1)) * SROWS + node;
    if (nd < n) {
        int dg = deg[nd];
        float dv = rsqrtf((float)dg + 1.0f);
        const __half* hrow = Hs + (size_t)nd * 16;
        float h1[16];
#pragma unroll
        for (int c = 0; c < 16; ++c) {
            float v = dv * (unpack_acc(acc64, node, c, dg) + __half2float(hrow[c])) + b0s[c];
            h1[c] = v > 0.f ? v : 0.f;
        }
        float o[4];
#pragma unroll
        for (int j = 0; j < 4; ++j) {
            float sum = 0.f;
#pragma unroll
            for (int c = 0; c < 16; ++c) sum += h1[c] * w2s[c * 16 + qq * 4 + j];
            o[j] = sum * dv;
        }
        union { __half2 h[2]; uint2 u; } pk;
        pk.h[0] = __floats2half2_rn(o[0], o[1]);
        pk.h[1] = __floats2half2_rn(o[2], o[3]);
        *reinterpret_cast<uint2*>(Hs2 + (size_t)nd * 16 + qq * 4) = pk.u;
    }
}

// ---------------- conv2: gather + finalize + fused heads -> out ----------------
__global__ void __launch_bounds__(BLK, 8)
k_bconv2(const int* __restrict__ ftot, const int* __restrict__ fslab,
         const __half* __restrict__ Hs, const int* __restrict__ deg,
         const float* __restrict__ b2,
         const float* __restrict__ w_mem, const float* __restrict__ b_mem,
         const float* __restrict__ w_node, const float* __restrict__ b_node,
         float* __restrict__ out, int n) {
    __shared__ u64 acc64[SROWS][9];
    __shared__ float wms[16], wn0[16], wn1[16], b2s[16];
    int tid = threadIdx.x;
    for (int t = tid; t < SROWS * 9; t += BLK) ((u64*)acc64)[t] = 0ull;
    if (tid < 16) {
        wms[tid] = w_mem[tid];
        wn0[tid] = w_node[tid * 2 + 0];
        wn1[tid] = w_node[tid * 2 + 1];
        b2s[tid] = b2[tid];
    }
    __syncthreads();
    int fb = blockIdx.x;
    gather_fb(ftot, fslab, fb, reinterpret_cast<const uint4*>(Hs), acc64, tid);
    __syncthreads();
    int nd = (fb >> 4) * CNODES + (fb & (NSL - 1)) * SROWS + tid;
    if (tid < SROWS && nd < n) {
        int dg = deg[nd];
        float dv = rsqrtf((float)dg + 1.0f);
        const __half* hrow = Hs + (size_t)nd * 16;
        float mph = b_mem[0];
        float n0 = b_node[0];
        float n1 = b_node[1];
#pragma unroll
        for (int c = 0; c < 16; ++c) {
            float v = dv * (unpack_acc(acc64, tid, c, dg) + __half2float(hrow[c])) + b2s[c];
            float h = v > 0.f ? v : 0.f;
            mph += h * wms[c];
            n0  += h * wn0[c];
            n1  += h * wn1[c];
        }
        out[nd] = mph;
        out[n + 2 * nd + 0] = n0;
        out[n + 2 * nd + 1] = n1;
    }
}

extern "C" void kernel_launch(void* const* d_in, const int* in_sizes, int n_in,
                              void* d_out, int out_size, void* d_ws, size_t ws_size,
                              hipStream_t stream) {
    const int*   edges     = (const int*)d_in[0];
    const int*   feat      = (const int*)d_in[1];
    const float* emb_user  = (const float*)d_in[2];
    const float* emb_known = (const float*)d_in[3];
    const float* w_user    = (const float*)d_in[4];
    const float* b_user    = (const float*)d_in[5];
    const float* emb_cat   = (const float*)d_in[6];
    const float* w_cat     = (const float*)d_in[7];
    const float* b_cat     = (const float*)d_in[8];
    const float* w0        = (const float*)d_in[9];
    const float* b0        = (const float*)d_in[10];
    const float* w2        = (const float*)d_in[11];
    const float* b2        = (const float*)d_in[12];
    const float* w_node    = (const float*)d_in[13];
    const float* b_node    = (const float*)d_in[14];
    const float* w_mem     = (const float*)d_in[15];
    const float* b_mem     = (const float*)d_in[16];

    const int E = in_sizes[0] / 2;
    const int n = in_sizes[1] / 3;
    const int user_max = in_sizes[2] / 8 - 1;
    const int cat_max  = in_sizes[6] / 4 - 1;
    const int NBC = cdiv(n, CNODES);   // 98 for n=100000
    const int NBF = NBC * NSL;         // 1568 fine buckets

    const int* src = edges;
    const int* dst = edges + E;

    // workspace layout
    int* cslab   = (int*)d_ws;                                 // NBC*CAP (~16 MB)
    int* fslab   = cslab + (size_t)NBC * CAP;                  // NBF*NCHK*FCAP2 (~19.3 MB)
    __half* hsA  = (__half*)(fslab + (size_t)NBF * NCHK * FCAP2); // 16n halfs
    __half* hsB  = hsA + (size_t)n * 16;                       // 16n halfs
    int* gcur    = (int*)(hsB + (size_t)n * 16);               // NBC (relative cursors)
    int* deg     = gcur + NBC;                                 // n (zeroed together)
    int* ftot    = deg + n;                                    // NBF*NCHK

    float* outp = (float*)d_out;

    hipMemsetAsync(gcur, 0, (size_t)(NBC + n) * sizeof(int), stream);
    k_part<<<NPB, PBLK, 0, stream>>>(src, dst, gcur, cslab, E, NBC);
    k_refine<<<NBC * NCHK, PBLK, 0, stream>>>(gcur, cslab, fslab, ftot, deg, n);
    k_featmm<<<cdiv(n, BLK), BLK, 0, stream>>>(feat, emb_user, emb_known, w_user, b_user,
                                               emb_cat, w_cat, b_cat, w0, deg, hsA,
                                               n, user_max, cat_max);
    k_bconv1<<<NBF, BLK, 0, stream>>>(ftot, fslab, hsA, deg, b0, w2, hsB, n);
    k_bconv2<<<NBF, BLK, 0, stream>>>(ftot, fslab, hsB, deg, b2,
                                      w_mem, b_mem, w_node, b_node, outp, n);
}

// Round 21
// 100.814 us; speedup vs baseline: 1.0597x; 1.0597x over previous
//
#include <hip/hip_runtime.h>
#include <hip/hip_fp16.h>

#define BLK 256
#define PBLK 1024             // threads per partition block
#define NPB 256               // partition blocks == chunks
#define CSHIFT 10             // 1024 dst nodes per coarse bucket
#define CNODES 1024
#define CMASK 1023
#define NBCMAX 128            // max coarse buckets (n <= 131072)
#define CAP 40960             // coarse slab slots per bucket (mean ~32.6K + pad; >30 sigma)
#define SSHIFT 6              // slice bits 6..9 -> 16 slices of 64 nodes
#define NSL 16
#define SROWS 64
#define SRMASK 63
#define NCHK 8                // positional chunks per bucket for refine
#define FCAP2 384             // slots per (bucket,slice,chunk); mean ~255, +8 sigma
#define FXS 1048576.0f        // 2^20 fixed-point scale for LDS accumulation
#define FXI (1.0f / 1048576.0f)
#define PBIAS (1 << 23)       // per-addend bias so packed 32+32 halves stay non-negative

typedef int v4i __attribute__((ext_vector_type(4)));
typedef unsigned long long u64;

static inline int cdiv(int a, int b) { return (a + b - 1) / b; }

// ---------------- fused partition: local hist -> atomic run reservation -> scatter ----------------
// One read of edges from HBM; second pass hits L2 (chunk ~100 KB/block).
// Run order within a bucket is nondeterministic, but all consumers compute exact
// integer sums, so final outputs are order-independent.
__global__ void __launch_bounds__(PBLK)
k_part(const int* __restrict__ src, const int* __restrict__ dst,
       int* __restrict__ gcur, int* __restrict__ slab, int e, int nb) {
    __shared__ int hist[4][NBCMAX];
    __shared__ int curs[NBCMAX];
    __shared__ int rend[NBCMAX];
    int tid = threadIdx.x;
    int rep = (tid >> 6) & 3;
    for (int t = tid; t < 4 * NBCMAX; t += PBLK) ((int*)hist)[t] = 0;
    __syncthreads();
    int per = ((e + (int)gridDim.x - 1) / (int)gridDim.x + 3) & ~3;
    int beg = blockIdx.x * per;
    int end = min(e, beg + per);
    // pass 1: local histogram (cached loads -> chunk becomes L2-resident)
    if (beg < end) {
        int m4 = beg + ((end - beg) & ~3);
        for (int i = beg + tid * 4; i < m4; i += PBLK * 4) {
            v4i d4 = *reinterpret_cast<const v4i*>(dst + i);
            atomicAdd(&hist[rep][d4[0] >> CSHIFT], 1);
            atomicAdd(&hist[rep][d4[1] >> CSHIFT], 1);
            atomicAdd(&hist[rep][d4[2] >> CSHIFT], 1);
            atomicAdd(&hist[rep][d4[3] >> CSHIFT], 1);
        }
        int it = m4 + tid;
        if (it < end) atomicAdd(&hist[rep][dst[it] >> CSHIFT], 1);
    }
    __syncthreads();
    // reserve 16-aligned runs via one global atomic per (block,bucket)
    for (int b = tid; b < nb; b += PBLK) {
        int cnt = hist[0][b] + hist[1][b] + hist[2][b] + hist[3][b];
        int r16 = (cnt + 15) & ~15;
        int base = 0;
        if (r16) base = atomicAdd(&gcur[b], r16);
        int a0 = b * CAP + min(base, CAP);
        int a1 = b * CAP + min(base + r16, CAP);
        curs[b] = a0;
        rend[b] = a1;
    }
    __syncthreads();
    // pass 2: scatter (reads hit L2)
    if (beg < end) {
        int m4 = beg + ((end - beg) & ~3);
        for (int i = beg + tid * 4; i < m4; i += PBLK * 4) {
            v4i s4 = *reinterpret_cast<const v4i*>(src + i);
            v4i d4 = *reinterpret_cast<const v4i*>(dst + i);
#pragma unroll
            for (int k = 0; k < 4; ++k) {
                int d = d4[k];
                int b = d >> CSHIFT;
                int pos = atomicAdd(&curs[b], 1);
                if (pos < rend[b]) slab[pos] = (s4[k] << CSHIFT) | (d & CMASK);
            }
        }
        int it = m4 + tid;
        if (it < end) {
            int d = dst[it];
            int b = d >> CSHIFT;
            int pos = atomicAdd(&curs[b], 1);
            if (pos < rend[b]) slab[pos] = (src[it] << CSHIFT) | (d & CMASK);
        }
    }
    __syncthreads();
    // pad run tails to the 16-aligned reservation end with -1
    for (int b = tid; b < nb; b += PBLK) {
        for (int x = curs[b]; x < rend[b]; ++x) slab[x] = -1;
    }
}

// ---------------- pass D: chunked refine -> 16 fine segments per (bucket,chunk) + degree ----------------
__global__ void __launch_bounds__(PBLK)
k_refine(const int* __restrict__ tot, const int* __restrict__ cslab,
         int* __restrict__ fslab, int* __restrict__ ftot,
         int* __restrict__ deg, int n) {
    __shared__ int cur[NSL];
    __shared__ int cnt[CNODES];
    int tid = threadIdx.x;
    int b = blockIdx.x >> 3;
    int p = blockIdx.x & 7;
    if (tid < NSL) cur[tid] = 0;
    for (int t = tid; t < CNODES; t += PBLK) cnt[t] = 0;
    __syncthreads();
    int nlines = min(tot[b], CAP) >> 4;       // tot is a multiple of 16
    int q0 = ((p * nlines) >> 3) << 2;        // chunk start, int4 units (16-aligned slots)
    int q1 = (((p + 1) * nlines) >> 3) << 2;  // chunk end
    const v4i* sl4 = reinterpret_cast<const v4i*>(cslab + (size_t)b * CAP);
    for (int i = q0 + tid; i < q1; i += PBLK) {
        v4i e4 = sl4[i];
#pragma unroll
        for (int k = 0; k < 4; ++k) {
            int e = e4[k];
            if (e >= 0) {
                int s = (e >> SSHIFT) & (NSL - 1);
                int fe = ((e >> CSHIFT) << SSHIFT) | (e & SRMASK);
                atomicAdd(&cnt[e & CMASK], 1);
                int pos = atomicAdd(&cur[s], 1);
                if (pos < FCAP2) fslab[(size_t)((b * NSL + s) * NCHK + p) * FCAP2 + pos] = fe;
            }
        }
    }
    __syncthreads();
    if (tid < NSL) {
        int cc = min(cur[tid], FCAP2);
        int r = min((cc + 15) & ~15, FCAP2);
        int* seg = fslab + (size_t)((b * NSL + tid) * NCHK + p) * FCAP2;
        for (int x = cc; x < r; ++x) seg[x] = -1;
        ftot[(b * NSL + tid) * NCHK + p] = r;
    }
    for (int t = tid; t < CNODES; t += PBLK) {
        int v = cnt[t];
        int nd = b * CNODES + t;
        if (v && nd < n) atomicAdd(&deg[nd], v);
    }
}

// ---------------- fused: feature encode -> @W0 -> *dinv -> Hs[n,16] (f16) ----------------
__global__ void k_featmm(const int* __restrict__ feat,
                         const float* __restrict__ emb_user,
                         const float* __restrict__ emb_known,
                         const float* __restrict__ w_user,
                         const float* __restrict__ b_user,
                         const float* __restrict__ emb_cat,
                         const float* __restrict__ w_cat,
                         const float* __restrict__ b_cat,
                         const float* __restrict__ w0,
                         const int* __restrict__ deg,
                         __half* __restrict__ Hs,
                         int n, int user_max, int cat_max) {
    __shared__ float w0s[8 * 16];
    for (int t = threadIdx.x; t < 8 * 16; t += blockDim.x) w0s[t] = w0[t];
    __syncthreads();
    int i = blockIdx.x * blockDim.x + threadIdx.x;
    if (i >= n) return;
    int col0 = feat[i * 3 + 0];
    int col1 = feat[i * 3 + 1];
    int typ  = feat[i * 3 + 2];
    float x[8];
    if (typ == 0) {
        int u = min(max(col0, 0), user_max);
        int k = min(max(col1, 0), 1);
        const float4* eu = reinterpret_cast<const float4*>(emb_user + (size_t)u * 8);
        const float4* ek = reinterpret_cast<const float4*>(emb_known + (size_t)k * 8);
        float4 a0 = eu[0], a1 = eu[1], k0 = ek[0], k1 = ek[1];
        float in[8];
        in[0] = fmaxf(a0.x + k0.x, 0.f); in[1] = fmaxf(a0.y + k0.y, 0.f);
        in[2] = fmaxf(a0.z + k0.z, 0.f); in[3] = fmaxf(a0.w + k0.w, 0.f);
        in[4] = fmaxf(a1.x + k1.x, 0.f); in[5] = fmaxf(a1.y + k1.y, 0.f);
        in[6] = fmaxf(a1.z + k1.z, 0.f); in[7] = fmaxf(a1.w + k1.w, 0.f);
#pragma unroll
        for (int c = 0; c < 8; ++c) {
            float s = b_user[c];
#pragma unroll
            for (int d = 0; d < 8; ++d) s += in[d] * w_user[d * 8 + c];
            x[c] = s;
        }
    } else {
        int ci = min(max(col0, 0), cat_max);
        float4 c0 = reinterpret_cast<const float4*>(emb_cat + (size_t)ci * 4)[0];
        float in[4];
        in[0] = fmaxf(c0.x, 0.f); in[1] = fmaxf(c0.y, 0.f);
        in[2] = fmaxf(c0.z, 0.f); in[3] = fmaxf(c0.w, 0.f);
#pragma unroll
        for (int c = 0; c < 8; ++c) {
            float s = b_cat[c];
#pragma unroll
            for (int d = 0; d < 4; ++d) s += in[d] * w_cat[d * 8 + c];
            x[c] = s;
        }
    }
    float dv = rsqrtf((float)deg[i] + 1.0f);
    float o[16];
#pragma unroll
    for (int c = 0; c < 16; ++c) {
        float s = 0.f;
#pragma unroll
        for (int d = 0; d < 8; ++d) s += x[d] * w0s[d * 16 + c];
        o[c] = s * dv;
    }
    union { __half2 h[8]; uint4 u[2]; } pk;
#pragma unroll
    for (int k = 0; k < 8; ++k) pk.h[k] = __floats2half2_rn(o[2 * k], o[2 * k + 1]);
    uint4* dp = reinterpret_cast<uint4*>(Hs + (size_t)i * 16);
    dp[0] = pk.u[0];
    dp[1] = pk.u[1];
}

// ---------------- paired-segment 8-deep gather with packed u64 LDS atomics ----------------
__device__ __forceinline__ void gather_pair(const int* __restrict__ run0, int n0,
                                            const int* __restrict__ run1, int n1,
                                            const uint4* __restrict__ Hs4,
                                            u64 (*acc64)[9], int tid) {
    const v4i* sl0 = reinterpret_cast<const v4i*>(run0);
    const v4i* sl1 = reinterpret_cast<const v4i*>(run1);
    int ns0 = n0 >> 2, ns1 = n1 >> 2;
    int maxs = max(ns0, ns1);
    int g = tid >> 1, q = tid & 1;    // 128 lane-pairs; q owns channels 8q..8q+7
    for (int base = 0; base < maxs; base += 128) {
        int i = base + g;
        v4i e0 = sl0[min(i, (FCAP2 >> 2) - 1)];
        v4i e1 = sl1[min(i, (FCAP2 >> 2) - 1)];
        bool b0 = i < ns0, b1 = i < ns1;
        int us[8];
        us[0] = b0 ? e0[0] : -1; us[1] = b0 ? e0[1] : -1;
        us[2] = b0 ? e0[2] : -1; us[3] = b0 ? e0[3] : -1;
        us[4] = b1 ? e1[0] : -1; us[5] = b1 ? e1[1] : -1;
        us[6] = b1 ? e1[2] : -1; us[7] = b1 ? e1[3] : -1;
        uint4 v[8];
#pragma unroll
        for (int k = 0; k < 8; ++k)
            if (us[k] >= 0) v[k] = Hs4[(size_t)(us[k] >> SSHIFT) * 2 + q];
#pragma unroll
        for (int k = 0; k < 8; ++k) {
            if (us[k] >= 0) {
                int dl = us[k] & SRMASK;
                union { uint4 u4; __half2 h[4]; } c;
                c.u4 = v[k];
#pragma unroll
                for (int j = 0; j < 4; ++j) {
                    float2 f = __half22float2(c.h[j]);
                    unsigned a0 = (unsigned)(__float2int_rn(f.x * FXS) + PBIAS);
                    unsigned a1 = (unsigned)(__float2int_rn(f.y * FXS) + PBIAS);
                    u64 pk = ((u64)a1 << 32) | (u64)a0;
                    atomicAdd(&acc64[dl][q * 4 + j], pk);
                }
            }
        }
    }
}

__device__ __forceinline__ void gather_fb(const int* __restrict__ ftot,
                                          const int* __restrict__ fslab,
                                          int fb, const uint4* __restrict__ Hs4,
                                          u64 (*acc64)[9], int tid) {
#pragma unroll
    for (int p = 0; p < NCHK; p += 2) {
        const int* r0 = fslab + (size_t)(fb * NCHK + p) * FCAP2;
        const int* r1 = fslab + (size_t)(fb * NCHK + p + 1) * FCAP2;
        gather_pair(r0, ftot[fb * NCHK + p], r1, ftot[fb * NCHK + p + 1], Hs4, acc64, tid);
    }
}

// unpack channel c for node: acc64[node][c>>1], minus deg*BIAS
__device__ __forceinline__ float unpack_acc(const u64 (*acc64)[9], int node, int c, int dg) {
    u64 w = acc64[node][c >> 1];
    unsigned raw = (c & 1) ? (unsigned)(w >> 32) : (unsigned)(w & 0xffffffffULL);
    long long t = (long long)raw - (long long)dg * PBIAS;
    return (float)t * FXI;
}

// ---------------- conv1: gather + parallel finalize + fused @W2*dinv -> Hs2 (f16) ----------------
__global__ void __launch_bounds__(BLK, 8)
k_bconv1(const int* __restrict__ ftot, const int* __restrict__ fslab,
         const __half* __restrict__ Hs, const int* __restrict__ deg,
         const float* __restrict__ b0, const float* __restrict__ w2,
         __half* __restrict__ Hs2, int n) {
    __shared__ u64 acc64[SROWS][9];
    __shared__ float w2s[16 * 16];
    __shared__ float b0s[16];
    int tid = threadIdx.x;
    for (int t = tid; t < SROWS * 9; t += BLK) ((u64*)acc64)[t] = 0ull;
    w2s[tid] = w2[tid];          // BLK == 256 == 16*16
    if (tid < 16) b0s[tid] = b0[tid];
    __syncthreads();
    int fb = blockIdx.x;
    gather_fb(ftot, fslab, fb, reinterpret_cast<const uint4*>(Hs), acc64, tid);
    __syncthreads();
    // parallel finalize: thread (node = tid&63, qq = tid>>6) computes 4 output channels
    int node = tid & 63;
    int qq = tid >> 6;
    int nd = (fb >> 4) * CNODES + (fb & (NSL - 1)) * SROWS + node;
    if (nd < n) {
        int dg = deg[nd];
        float dv = rsqrtf((float)dg + 1.0f);
        const __half* hrow = Hs + (size_t)nd * 16;
        float h1[16];
#pragma unroll
        for (int c = 0; c < 16; ++c) {
            float v = dv * (unpack_acc(acc64, node, c, dg) + __half2float(hrow[c])) + b0s[c];
            h1[c] = v > 0.f ? v : 0.f;
        }
        float o[4];
#pragma unroll
        for (int j = 0; j < 4; ++j) {
            float sum = 0.f;
#pragma unroll
            for (int c = 0; c < 16; ++c) sum += h1[c] * w2s[c * 16 + qq * 4 + j];
            o[j] = sum * dv;
        }
        union { __half2 h[2]; uint2 u; } pk;
        pk.h[0] = __floats2half2_rn(o[0], o[1]);
        pk.h[1] = __floats2half2_rn(o[2], o[3]);
        *reinterpret_cast<uint2*>(Hs2 + (size_t)nd * 16 + qq * 4) = pk.u;
    }
}

// ---------------- conv2: gather + finalize + fused heads -> out ----------------
__global__ void __launch_bounds__(BLK, 8)
k_bconv2(const int* __restrict__ ftot, const int* __restrict__ fslab,
         const __half* __restrict__ Hs, const int* __restrict__ deg,
         const float* __restrict__ b2,
         const float* __restrict__ w_mem, const float* __restrict__ b_mem,
         const float* __restrict__ w_node, const float* __restrict__ b_node,
         float* __restrict__ out, int n) {
    __shared__ u64 acc64[SROWS][9];
    __shared__ float wms[16], wn0[16], wn1[16], b2s[16];
    int tid = threadIdx.x;
    for (int t = tid; t < SROWS * 9; t += BLK) ((u64*)acc64)[t] = 0ull;
    if (tid < 16) {
        wms[tid] = w_mem[tid];
        wn0[tid] = w_node[tid * 2 + 0];
        wn1[tid] = w_node[tid * 2 + 1];
        b2s[tid] = b2[tid];
    }
    __syncthreads();
    int fb = blockIdx.x;
    gather_fb(ftot, fslab, fb, reinterpret_cast<const uint4*>(Hs), acc64, tid);
    __syncthreads();
    int nd = (fb >> 4) * CNODES + (fb & (NSL - 1)) * SROWS + tid;
    if (tid < SROWS && nd < n) {
        int dg = deg[nd];
        float dv = rsqrtf((float)dg + 1.0f);
        const __half* hrow = Hs + (size_t)nd * 16;
        float mph = b_mem[0];
        float n0 = b_node[0];
        float n1 = b_node[1];
#pragma unroll
        for (int c = 0; c < 16; ++c) {
            float v = dv * (unpack_acc(acc64, tid, c, dg) + __half2float(hrow[c])) + b2s[c];
            float h = v > 0.f ? v : 0.f;
            mph += h * wms[c];
            n0  += h * wn0[c];
            n1  += h * wn1[c];
        }
        out[nd] = mph;
        out[n + 2 * nd + 0] = n0;
        out[n + 2 * nd + 1] = n1;
    }
}

extern "C" void kernel_launch(void* const* d_in, const int* in_sizes, int n_in,
                              void* d_out, int out_size, void* d_ws, size_t ws_size,
                              hipStream_t stream) {
    const int*   edges     = (const int*)d_in[0];
    const int*   feat      = (const int*)d_in[1];
    const float* emb_user  = (const float*)d_in[2];
    const float* emb_known = (const float*)d_in[3];
    const float* w_user    = (const float*)d_in[4];
    const float* b_user    = (const float*)d_in[5];
    const float* emb_cat   = (const float*)d_in[6];
    const float* w_cat     = (const float*)d_in[7];
    const float* b_cat     = (const float*)d_in[8];
    const float* w0        = (const float*)d_in[9];
    const float* b0        = (const float*)d_in[10];
    const float* w2        = (const float*)d_in[11];
    const float* b2        = (const float*)d_in[12];
    const float* w_node    = (const float*)d_in[13];
    const float* b_node    = (const float*)d_in[14];
    const float* w_mem     = (const float*)d_in[15];
    const float* b_mem     = (const float*)d_in[16];

    const int E = in_sizes[0] / 2;
    const int n = in_sizes[1] / 3;
    const int user_max = in_sizes[2] / 8 - 1;
    const int cat_max  = in_sizes[6] / 4 - 1;
    const int NBC = cdiv(n, CNODES);   // 98 for n=100000
    const int NBF = NBC * NSL;         // 1568 fine buckets

    const int* src = edges;
    const int* dst = edges + E;

    // workspace layout
    int* cslab   = (int*)d_ws;                                 // NBC*CAP (~16 MB)
    int* fslab   = cslab + (size_t)NBC * CAP;                  // NBF*NCHK*FCAP2 (~19.3 MB)
    __half* hsA  = (__half*)(fslab + (size_t)NBF * NCHK * FCAP2); // 16n halfs
    __half* hsB  = hsA + (size_t)n * 16;                       // 16n halfs
    int* gcur    = (int*)(hsB + (size_t)n * 16);               // NBC (relative cursors)
    int* deg     = gcur + NBC;                                 // n (zeroed together)
    int* ftot    = deg + n;                                    // NBF*NCHK

    float* outp = (float*)d_out;

    hipMemsetAsync(gcur, 0, (size_t)(NBC + n) * sizeof(int), stream);
    k_part<<<NPB, PBLK, 0, stream>>>(src, dst, gcur, cslab, E, NBC);
    k_refine<<<NBC * NCHK, PBLK, 0, stream>>>(gcur, cslab, fslab, ftot, deg, n);
    k_featmm<<<cdiv(n, BLK), BLK, 0, stream>>>(feat, emb_user, emb_known, w_user, b_user,
                                               emb_cat, w_cat, b_cat, w0, deg, hsA,
                                               n, user_max, cat_max);
    k_bconv1<<<NBF, BLK, 0, stream>>>(ftot, fslab, hsA, deg, b0, w2, hsB, n);
    k_bconv2<<<NBF, BLK, 0, stream>>>(ftot, fslab, hsB, deg, b2,
                                      w_mem, b_mem, w_node, b_node, outp, n);
}